// Round 6
// baseline (39.420 us; speedup 1.0000x reference)
//
#include <hip/hip_runtime.h>

namespace {
constexpr int L_LEN   = 4096;   // sequence length
constexpr int NTAPS   = 128;    // truncated filter length
constexpr int NH      = 768;    // heads
constexpr int KSTRIDE = 4096;   // k row stride
constexpr int TPB     = 256;    // 4 waves
constexpr int PADB    = 160;    // left zero pad in bf16 elems (10 blocks of 16)
constexpr int XB      = PADB + L_LEN;  // 4256 bf16 staged per row
constexpr int NP      = 5;      // K-pairs: q = (0,1),(2,3),(4,5),(6,7),(8,9-zero)
constexpr size_t AWS_BYTES = (size_t)NH * NP * 64 * 16;  // 3.93 MB of A-fragments

typedef __attribute__((ext_vector_type(8))) short  short8;  // 8 bf16 (4 VGPRs)
typedef __attribute__((ext_vector_type(4))) float  f32x4;   // MFMA accumulator

// XOR-swizzle: flip byte-bit4 by byte-bit7 -> spreads 32B-strided b128 reads across banks.
__device__ __forceinline__ unsigned swz(unsigned byte) {
    return byte ^ (((byte >> 7) & 1u) << 4);
}
// fp32 -> bf16 round-to-nearest-even (proven rounds 1-2)
__device__ __forceinline__ unsigned short f2bf(float f) {
    unsigned u = __builtin_bit_cast(unsigned, f);
    u += 0x7FFFu + ((u >> 16) & 1u);
    return (unsigned short)(u >> 16);
}
} // namespace

// ---------- pre-kernel: per-head Toeplitz A-fragments -> d_ws ----------
// A[i][kk] = k[t], t = 16*q + i - j;  kk = 8*g + e, q = 2p + (g>>1), j = 8*(g&1) + e
// One wave per head, 4 heads per block, 192 blocks total.
__global__ __launch_bounds__(TPB) void build_afrag(
    const float* __restrict__ kf, short8* __restrict__ aws) {
    __shared__ float sk4[4][NTAPS];
    const int tid = threadIdx.x;
    const int h0  = blockIdx.x * 4;

    // stage 4 head rows (128 f32 each): threads 0..127, one float4 each, coalesced per head
    if (tid < 128) {
        const int hh = tid >> 5;          // 0..3
        const int q  = tid & 31;          // float4 index within row
        ((float4*)sk4[hh])[q] = ((const float4*)(kf + (size_t)(h0 + hh) * KSTRIDE))[q];
    }
    __syncthreads();

    const int wave = tid >> 6;            // head within block
    const int lane = tid & 63;
    const int i    = lane & 15;
    const int g    = lane >> 4;
    const int h    = h0 + wave;
    #pragma unroll
    for (int p = 0; p < NP; ++p) {
        const int tbase = 32 * p + 16 * (g >> 1) + i - 8 * (g & 1);
        short8 a;
        #pragma unroll
        for (int e = 0; e < 8; ++e) {
            const int t = tbase - e;
            const float kv = (t >= 0 && t < NTAPS) ? sk4[wave][t] : 0.0f;
            a[e] = (short)f2bf(kv);
        }
        aws[((size_t)h * NP + p) * 64 + lane] = a;   // 1 KB coalesced store per wave
    }
}

// ---------- main kernel: lean (no skf, no A-build) ----------
__global__ __launch_bounds__(TPB) void pconv_mfma(
    const float* __restrict__ x, const short8* __restrict__ aws, float* __restrict__ y) {
    __shared__ unsigned char sxb[XB * 2];     // x row as bf16, swizzled

    const int tid = threadIdx.x;
    const int row = blockIdx.x;               // b*768 + h
    const int h   = row % NH;
    const int lane = tid & 63;
    const int i    = lane & 15;
    const int g    = lane >> 4;

    // issue A-fragment loads first (L2/L3-hot, 1 KB coalesced per wave per p)
    const short8* aw = aws + (size_t)h * NP * 64 + lane;
    short8 afrag[NP];
    #pragma unroll
    for (int p = 0; p < NP; ++p) afrag[p] = aw[(size_t)p * 64];

    // zero left pad: 320 bytes as 40 x 8B
    if (tid < PADB / 4)
        *(unsigned long long*)(sxb + swz(8u * tid)) = 0ull;

    // stage x row: coalesced float4 loads -> bf16 -> swizzled 8B LDS writes
    const float* xr = x + (size_t)row * L_LEN;
    #pragma unroll
    for (int s = 0; s < L_LEN / (TPB * 4); ++s) {           // 4 iters
        const int q4 = tid + s * TPB;
        const float4 v = ((const float4*)xr)[q4];
        unsigned long long pk =
            (unsigned long long)f2bf(v.x)
          | ((unsigned long long)f2bf(v.y) << 16)
          | ((unsigned long long)f2bf(v.z) << 32)
          | ((unsigned long long)f2bf(v.w) << 48);
        *(unsigned long long*)(sxb + swz(2u * PADB + 8u * q4)) = pk;
    }
    __syncthreads();

    // 4 tiles per wave: C[16 i x 16 n] over 16 consecutive m-blocks
    const int wave = tid >> 6;
    float* yr = y + (size_t)row * L_LEN;
    #pragma unroll
    for (int tt = 0; tt < 4; ++tt) {
        const int m0 = (wave * 4 + tt) * 16;  // first m-block of this tile
        f32x4 acc = {0.f, 0.f, 0.f, 0.f};
        #pragma unroll
        for (int p = 0; p < NP; ++p) {
            // B[kk][n] = x_pad[16*(m0 + n - 2p - (g>>1)) + 8*(g&1) + e], n = i
            const unsigned raw = 32u * (unsigned)(10 + m0 + i - 2 * p - (g >> 1))
                               + 16u * (unsigned)(g & 1);
            const short8 b = *(const short8*)(sxb + swz(raw));
            acc = __builtin_amdgcn_mfma_f32_16x16x32_bf16(afrag[p], b, acc, 0, 0, 0);
        }
        // C layout: col n = lane&15 (= i), row = 4*g + r  ->  y[16*(m0+n) + 4g + r].
        // Wave covers a contiguous (lane-permuted) 1 KB span -> fully coalesced.
        // nt: y is write-once -> don't evict x from L2/L3.
        __builtin_nontemporal_store(acc, (f32x4*)(yr + 16 * (m0 + i) + 4 * g));
    }
}

// ---------- fallback (proven round-5 single kernel) if ws is too small ----------
__global__ __launch_bounds__(TPB) void pconv_mfma_fb(
    const float* __restrict__ x, const float* __restrict__ kf, float* __restrict__ y) {
    __shared__ float         skf[NTAPS];
    __shared__ unsigned char sxb[XB * 2];

    const int tid = threadIdx.x;
    const int row = blockIdx.x;
    const int h   = row % NH;

    if (tid < NTAPS / 4)
        ((float4*)skf)[tid] = ((const float4*)(kf + (size_t)h * KSTRIDE))[tid];
    if (tid < PADB / 4)
        *(unsigned long long*)(sxb + swz(8u * tid)) = 0ull;

    const float* xr = x + (size_t)row * L_LEN;
    #pragma unroll
    for (int s = 0; s < L_LEN / (TPB * 4); ++s) {
        const int q4 = tid + s * TPB;
        const float4 v = ((const float4*)xr)[q4];
        unsigned long long pk =
            (unsigned long long)f2bf(v.x)
          | ((unsigned long long)f2bf(v.y) << 16)
          | ((unsigned long long)f2bf(v.z) << 32)
          | ((unsigned long long)f2bf(v.w) << 48);
        *(unsigned long long*)(sxb + swz(2u * PADB + 8u * q4)) = pk;
    }
    __syncthreads();

    const int lane = tid & 63;
    const int i    = lane & 15;
    const int g    = lane >> 4;
    short8 afrag[NP];
    #pragma unroll
    for (int p = 0; p < NP; ++p) {
        const int tbase = 32 * p + 16 * (g >> 1) + i - 8 * (g & 1);
        short8 a;
        #pragma unroll
        for (int e = 0; e < 8; ++e) {
            const int t = tbase - e;
            const float kv = (t >= 0 && t < NTAPS) ? skf[t] : 0.0f;
            a[e] = (short)f2bf(kv);
        }
        afrag[p] = a;
    }

    const int wave = tid >> 6;
    float* yr = y + (size_t)row * L_LEN;
    #pragma unroll
    for (int tt = 0; tt < 4; ++tt) {
        const int m0 = (wave * 4 + tt) * 16;
        f32x4 acc = {0.f, 0.f, 0.f, 0.f};
        #pragma unroll
        for (int p = 0; p < NP; ++p) {
            const unsigned raw = 32u * (unsigned)(10 + m0 + i - 2 * p - (g >> 1))
                               + 16u * (unsigned)(g & 1);
            const short8 b = *(const short8*)(sxb + swz(raw));
            acc = __builtin_amdgcn_mfma_f32_16x16x32_bf16(afrag[p], b, acc, 0, 0, 0);
        }
        __builtin_nontemporal_store(acc, (f32x4*)(yr + 16 * (m0 + i) + 4 * g));
    }
}

extern "C" void kernel_launch(void* const* d_in, const int* in_sizes, int n_in,
                              void* d_out, int out_size, void* d_ws, size_t ws_size,
                              hipStream_t stream) {
    const float* x = (const float*)d_in[0];   // [8, 768, 4096] f32
    const float* k = (const float*)d_in[1];   // [768, 4096] f32 (first 128 taps used)
    float* y = (float*)d_out;                 // [8, 768, 4096] f32
    const int rows = in_sizes[0] / L_LEN;     // 6144

    if (ws_size >= AWS_BYTES && d_ws != nullptr) {
        short8* aws = (short8*)d_ws;
        hipLaunchKernelGGL(build_afrag, dim3(NH / 4), dim3(TPB), 0, stream, k, aws);
        hipLaunchKernelGGL(pconv_mfma, dim3(rows), dim3(TPB), 0, stream, x, aws, y);
    } else {
        hipLaunchKernelGGL(pconv_mfma_fb, dim3(rows), dim3(TPB), 0, stream, x, k, y);
    }
}

// Round 8
// 35.383 us; speedup vs baseline: 1.1141x; 1.1141x over previous
//
#include <hip/hip_runtime.h>

namespace {
constexpr int L_LEN   = 4096;   // sequence length
constexpr int NTAPS   = 128;    // truncated filter length
constexpr int NH      = 768;    // heads
constexpr int KSTRIDE = 4096;   // k row stride
constexpr int TPB     = 256;    // 4 waves
constexpr int PADB    = 160;    // left zero pad in bf16 elems (10 blocks of 16)
constexpr int XB      = PADB + L_LEN;  // 4256 bf16 staged per row
constexpr int XBB     = XB * 2;        // 8512 bytes per row buffer (16B-aligned)
constexpr int NP      = 5;      // K-pairs: q = (0,1),(2,3),(4,5),(6,7),(8,9-zero)

typedef __attribute__((ext_vector_type(8))) short  short8;  // 8 bf16 (4 VGPRs)
typedef __attribute__((ext_vector_type(4))) float  f32x4;   // MFMA accumulator

// XOR-swizzle: flip byte-bit4 by byte-bit7 -> spreads 32B-strided b128 reads across banks.
__device__ __forceinline__ unsigned swz(unsigned byte) {
    return byte ^ (((byte >> 7) & 1u) << 4);
}
// fp32 -> bf16 round-to-nearest-even (proven rounds 1-5)
__device__ __forceinline__ unsigned short f2bf(float f) {
    unsigned u = __builtin_bit_cast(unsigned, f);
    u += 0x7FFFu + ((u >> 16) & 1u);
    return (unsigned short)(u >> 16);
}
} // namespace

// Two rows (same head h, batches 2*pr and 2*pr+1) per block, software-pipelined:
// all global loads issued up front (128B/thread MLP); A-build sits AFTER barrier 1
// (skf is wave0-written -> needs the barrier; race caused round-7 failure) and
// overlaps row-B load latency; row-B pack waits on loads that had all of row-A
// compute to land.
__global__ __launch_bounds__(TPB) void pconv_mfma2(
    const float* __restrict__ x, const float* __restrict__ kf, float* __restrict__ y) {
    __shared__ float         skf[NTAPS];
    __shared__ unsigned char sxb[2][XBB];

    const int tid = threadIdx.x;
    const int bid = blockIdx.x;               // 0..3071
    const int h   = bid % NH;
    const int pr  = bid / NH;                 // 0..3
    const int rowA = (2 * pr)     * NH + h;
    const int rowB = (2 * pr + 1) * NH + h;

    // ---- issue ALL global loads first: 2 rows x 4 float4 per thread ----
    const float* xrA = x + (size_t)rowA * L_LEN;
    const float* xrB = x + (size_t)rowB * L_LEN;
    float4 vA[4], vB[4];
    #pragma unroll
    for (int s = 0; s < 4; ++s) vA[s] = ((const float4*)xrA)[tid + s * TPB];
    #pragma unroll
    for (int s = 0; s < 4; ++s) vB[s] = ((const float4*)xrB)[tid + s * TPB];

    // filter stage (small, L2-hot; wave 0 only -> consumed after barrier 1)
    if (tid < NTAPS / 4)
        ((float4*)skf)[tid] = ((const float4*)(kf + (size_t)h * KSTRIDE))[tid];

    // zero left pads of both buffers (independent of loads)
    if (tid < PADB / 4) {
        *(unsigned long long*)(sxb[0] + swz(8u * tid)) = 0ull;
        *(unsigned long long*)(sxb[1] + swz(8u * tid)) = 0ull;
    }

    // ---- pack+write row A into buf0 (waits only on vA) ----
    #pragma unroll
    for (int s = 0; s < 4; ++s) {
        const int q4 = tid + s * TPB;
        const float4 v = vA[s];
        unsigned long long pk =
            (unsigned long long)f2bf(v.x)
          | ((unsigned long long)f2bf(v.y) << 16)
          | ((unsigned long long)f2bf(v.z) << 32)
          | ((unsigned long long)f2bf(v.w) << 48);
        *(unsigned long long*)(sxb[0] + swz(2u * PADB + 8u * q4)) = pk;
    }
    __syncthreads();   // barrier 1: skf, pads, and buf0 now visible to all waves

    // ---- build Toeplitz A fragments (after barrier; overlaps vB latency) ----
    // A[i][kk] = k[t], t = 16*q + i - j;  kk = 8*g + e, q = 2p + (g>>1), j = 8*(g&1) + e
    const int lane = tid & 63;
    const int i    = lane & 15;
    const int g    = lane >> 4;
    short8 afrag[NP];
    #pragma unroll
    for (int p = 0; p < NP; ++p) {
        const int tbase = 32 * p + 16 * (g >> 1) + i - 8 * (g & 1);
        short8 a;
        #pragma unroll
        for (int e = 0; e < 8; ++e) {
            const int t = tbase - e;
            const float kv = (t >= 0 && t < NTAPS) ? skf[t] : 0.0f;
            a[e] = (short)f2bf(kv);
        }
        afrag[p] = a;
    }

    const int wave = tid >> 6;

    // ---- compute + store row A from buf0 ----
    {
        float* yr = y + (size_t)rowA * L_LEN;
        #pragma unroll
        for (int tt = 0; tt < 4; ++tt) {
            const int m0 = (wave * 4 + tt) * 16;
            f32x4 acc = {0.f, 0.f, 0.f, 0.f};
            #pragma unroll
            for (int p = 0; p < NP; ++p) {
                const unsigned raw = 32u * (unsigned)(10 + m0 + i - 2 * p - (g >> 1))
                                   + 16u * (unsigned)(g & 1);
                const short8 b = *(const short8*)(sxb[0] + swz(raw));
                acc = __builtin_amdgcn_mfma_f32_16x16x32_bf16(afrag[p], b, acc, 0, 0, 0);
            }
            __builtin_nontemporal_store(acc, (f32x4*)(yr + 16 * (m0 + i) + 4 * g));
        }
    }

    // ---- pack+write row B into buf1 (vB landed during row-A compute) ----
    #pragma unroll
    for (int s = 0; s < 4; ++s) {
        const int q4 = tid + s * TPB;
        const float4 v = vB[s];
        unsigned long long pk =
            (unsigned long long)f2bf(v.x)
          | ((unsigned long long)f2bf(v.y) << 16)
          | ((unsigned long long)f2bf(v.z) << 32)
          | ((unsigned long long)f2bf(v.w) << 48);
        *(unsigned long long*)(sxb[1] + swz(2u * PADB + 8u * q4)) = pk;
    }
    __syncthreads();   // barrier 2: buf1 visible

    // ---- compute + store row B from buf1 ----
    {
        float* yr = y + (size_t)rowB * L_LEN;
        #pragma unroll
        for (int tt = 0; tt < 4; ++tt) {
            const int m0 = (wave * 4 + tt) * 16;
            f32x4 acc = {0.f, 0.f, 0.f, 0.f};
            #pragma unroll
            for (int p = 0; p < NP; ++p) {
                const unsigned raw = 32u * (unsigned)(10 + m0 + i - 2 * p - (g >> 1))
                                   + 16u * (unsigned)(g & 1);
                const short8 b = *(const short8*)(sxb[1] + swz(raw));
                acc = __builtin_amdgcn_mfma_f32_16x16x32_bf16(afrag[p], b, acc, 0, 0, 0);
            }
            __builtin_nontemporal_store(acc, (f32x4*)(yr + 16 * (m0 + i) + 4 * g));
        }
    }
}

extern "C" void kernel_launch(void* const* d_in, const int* in_sizes, int n_in,
                              void* d_out, int out_size, void* d_ws, size_t ws_size,
                              hipStream_t stream) {
    const float* x = (const float*)d_in[0];   // [8, 768, 4096] f32
    const float* k = (const float*)d_in[1];   // [768, 4096] f32 (first 128 taps used)
    float* y = (float*)d_out;                 // [8, 768, 4096] f32
    const int rows = in_sizes[0] / L_LEN;     // 6144
    hipLaunchKernelGGL(pconv_mfma2, dim3(rows / 2), dim3(TPB), 0, stream, x, k, y);
}